// Round 3
// baseline (11.211 us; speedup 1.0000x reference)
//
#include <hip/hip_runtime.h>
#include <hip/hip_bf16.h>

// Reference output = _fire(ap3): depends ONLY on ap3 (input index 4).
// All matmuls in the reference are dead code (h1/h2/h3 deleted, never used).
// fire: out[i] = ap3[i] > 15 ? +0.05 : (ap3[i] < 15 ? -0.05 : 0.0)
// (original code quirk: BOTH comparisons against +15, not -15)

__global__ void fire_ap3_kernel(const float* __restrict__ ap3,
                                float* __restrict__ out, int n4) {
    int i = blockIdx.x * blockDim.x + threadIdx.x;  // one float4 per thread
    if (i < n4) {
        float4 a = reinterpret_cast<const float4*>(ap3)[i];
        float4 r;
        r.x = a.x > 15.0f ? 0.05f : (a.x < 15.0f ? -0.05f : 0.0f);
        r.y = a.y > 15.0f ? 0.05f : (a.y < 15.0f ? -0.05f : 0.0f);
        r.z = a.z > 15.0f ? 0.05f : (a.z < 15.0f ? -0.05f : 0.0f);
        r.w = a.w > 15.0f ? 0.05f : (a.w < 15.0f ? -0.05f : 0.0f);
        reinterpret_cast<float4*>(out)[i] = r;
    }
}

// Scalar tail-safe fallback if out_size not divisible by 4 (it is: 4096).
__global__ void fire_ap3_scalar(const float* __restrict__ ap3,
                                float* __restrict__ out, int n) {
    int i = blockIdx.x * blockDim.x + threadIdx.x;
    if (i < n) {
        float a = ap3[i];
        out[i] = a > 15.0f ? 0.05f : (a < 15.0f ? -0.05f : 0.0f);
    }
}

extern "C" void kernel_launch(void* const* d_in, const int* in_sizes, int n_in,
                              void* d_out, int out_size, void* d_ws, size_t ws_size,
                              hipStream_t stream) {
    // setup_inputs order: x(0), x0(1), ap1(2), ap2(3), ap3(4), W1(5), b1(6), ...
    const float* ap3 = (const float*)d_in[4];
    float* out = (float*)d_out;

    if ((out_size & 3) == 0) {
        int n4 = out_size >> 2;                 // 1024 float4's
        int block = 256;
        int grid = (n4 + block - 1) / block;    // 4 blocks
        fire_ap3_kernel<<<grid, block, 0, stream>>>(ap3, out, n4);
    } else {
        int block = 256;
        int grid = (out_size + block - 1) / block;
        fire_ap3_scalar<<<grid, block, 0, stream>>>(ap3, out, out_size);
    }
}